// Round 5
// baseline (321.218 us; speedup 1.0000x reference)
//
#include <hip/hip_runtime.h>

#define C 256

typedef short s16x8 __attribute__((ext_vector_type(8)));
typedef float f32x4 __attribute__((ext_vector_type(4)));

#if __has_builtin(__builtin_amdgcn_exp2f)
#define EXP2F __builtin_amdgcn_exp2f
#else
#define EXP2F exp2f
#endif

__device__ __forceinline__ unsigned short f2b(float f) {
    unsigned u = __float_as_uint(f);
    unsigned r = (u + 0x7fffu + ((u >> 16) & 1u)) >> 16;
    return (unsigned short)r;
}

// pack bf16(a) lo16, bf16(b) hi16 (round-half-up) — one v_perm_b32
__device__ __forceinline__ unsigned pack2(float a, float b) {
    return __builtin_amdgcn_perm(__float_as_uint(b) + 0x8000u,
                                 __float_as_uint(a) + 0x8000u, 0x07060302u);
}

// ================= prep: cast+mean (img, aud) + weight transpose, one launch ==========
struct WPtrs { const float* src[8]; unsigned short* dst[8]; };

__device__ __forceinline__ void cast_mean_body(
    const float* __restrict__ x, unsigned short* __restrict__ y, float* __restrict__ part,
    int N, int nseg, int b, int seg, int tid) {
    __shared__ float red[4][C];
    int cg = tid & 63, rg = tid >> 6;
    int iters = nseg >> 2;
    const float* xp = x + ((size_t)b * N + (size_t)seg * nseg + rg) * C + cg * 4;
    unsigned short* yp = y + ((size_t)b * N + (size_t)seg * nseg + rg) * C + cg * 4;
    float s0 = 0.f, s1 = 0.f, s2 = 0.f, s3 = 0.f;
    for (int i = 0; i < iters; ++i) {
        float4 v = *(const float4*)(xp + (size_t)i * 4 * C);
        s0 += v.x; s1 += v.y; s2 += v.z; s3 += v.w;
        ushort4 o; o.x = f2b(v.x); o.y = f2b(v.y); o.z = f2b(v.z); o.w = f2b(v.w);
        *(ushort4*)(yp + (size_t)i * 4 * C) = o;
    }
    float4 s4 = {s0, s1, s2, s3};
    *(float4*)&red[rg][cg * 4] = s4;
    __syncthreads();
    float s = red[0][tid] + red[1][tid] + red[2][tid] + red[3][tid];
    part[(b * 8 + seg) * C + tid] = s;
}

__global__ void prep_kernel(const float* __restrict__ img, const float* __restrict__ aud,
                            unsigned short* __restrict__ R1, unsigned short* __restrict__ R4,
                            float* __restrict__ partI, float* __restrict__ partA, WPtrs wp) {
    int x = blockIdx.x, tid = threadIdx.x;
    if (x < 128) {
        cast_mean_body(img, R1, partI, 1024, 128, x >> 3, x & 7, tid);
    } else if (x < 256) {
        int id = x - 128;
        cast_mean_body(aud, R4, partA, 512, 64, id >> 3, id & 7, tid);
    } else {
        int id = x - 256;                 // 0..31
        const float* W = wp.src[id >> 2];
        unsigned short* Wt = wp.dst[id >> 2];
        int n = (id & 3) * 64 + (tid & 63);
        int k0 = (tid >> 6) * 64;
#pragma unroll
        for (int kk = 0; kk < 64; kk += 4) {
            float a0 = W[(size_t)(k0 + kk + 0) * C + n];
            float a1 = W[(size_t)(k0 + kk + 1) * C + n];
            float a2 = W[(size_t)(k0 + kk + 2) * C + n];
            float a3 = W[(size_t)(k0 + kk + 3) * C + n];
            ushort4 o; o.x = f2b(a0); o.y = f2b(a1); o.z = f2b(a2); o.w = f2b(a3);
            *(ushort4*)(Wt + (size_t)n * C + k0 + kk) = o;
        }
    }
}

// ================= multi-GEMM: several NT bf16 GEMMs (+ gates) in one launch ==========
struct GDesc {
    const unsigned short* A;   // [M][256]
    const unsigned short* Bt;  // [N][256]
    const float* bias;
    unsigned short* Yh;        // [M][N]
    int N;
    int start;                 // first block id
    int lnb;                   // log2(blocks along n)
    int bias_on_m;
    float oscale;
};
struct GArgs {
    GDesc d[4];
    int off1, off2, off3;      // desc start boundaries
    int gemm_total;            // blocks >= this do gate work
    const float* partI; const float* partA;
    const float* WgI; const float* WgA;
    const float* bgI; const float* bgA;
    float* gI; float* gA;
    float invNv, invNa;
};

__global__ __launch_bounds__(256, 2) void gemm_multi(GArgs ga) {
    __shared__ unsigned short sA[128 * 40];
    __shared__ unsigned short sB[64 * 40];
    const int bid = blockIdx.x;
    const int tid = threadIdx.x;

    if (bid >= ga.gemm_total) {  // ---- gate blocks: sigmoid(mean @ Wg + bg) ----
        float* t = (float*)sA;
        int id = bid - ga.gemm_total;
        int b = id >> 1, which = id & 1;
        const float* part = which ? ga.partA : ga.partI;
        const float* Wg = which ? ga.WgA : ga.WgI;
        const float* bg = which ? ga.bgA : ga.bgI;
        float* g = which ? ga.gA : ga.gI;
        float invN = which ? ga.invNa : ga.invNv;
        float s = 0.f;
#pragma unroll
        for (int j = 0; j < 8; ++j) s += part[(b * 8 + j) * C + tid];
        t[tid] = s * invN;
        __syncthreads();
        float acc = bg[tid];
#pragma unroll 8
        for (int k = 0; k < C; ++k) acc += t[k] * Wg[k * C + tid];
        g[b * C + tid] = 1.f / (1.f + __expf(-acc));
        return;
    }

    const int j = (bid >= ga.off1) + (bid >= ga.off2) + (bid >= ga.off3);
    const GDesc d = ga.d[j];
    const int local = bid - d.start;
    const int bn = (local & ((1 << d.lnb) - 1)) * 64;
    const int bm = (local >> d.lnb) * 128;

    const int wave = tid >> 6, lane = tid & 63;
    const int quad = lane >> 4, l16 = lane & 15;
    const int ar0 = tid >> 2, ac0 = tid & 3;
    const int ar1 = (tid + 256) >> 2;
    const int br = tid >> 2, bc = tid & 3;

    f32x4 acc[2][4];
#pragma unroll
    for (int i = 0; i < 2; ++i)
#pragma unroll
        for (int k = 0; k < 4; ++k) acc[i][k] = (f32x4){0.f, 0.f, 0.f, 0.f};

    uint4 pa0 = *(const uint4*)(d.A + (size_t)(bm + ar0) * 256 + ac0 * 8);
    uint4 pa1 = *(const uint4*)(d.A + (size_t)(bm + ar1) * 256 + ac0 * 8);
    uint4 pb  = *(const uint4*)(d.Bt + (size_t)(bn + br) * 256 + bc * 8);

    for (int k0 = 0; k0 < 256; k0 += 32) {
        __syncthreads();
        *(uint4*)(sA + ar0 * 40 + ac0 * 8) = pa0;
        *(uint4*)(sA + ar1 * 40 + ac0 * 8) = pa1;
        *(uint4*)(sB + br * 40 + bc * 8) = pb;
        if (k0 < 224) {
            pa0 = *(const uint4*)(d.A + (size_t)(bm + ar0) * 256 + k0 + 32 + ac0 * 8);
            pa1 = *(const uint4*)(d.A + (size_t)(bm + ar1) * 256 + k0 + 32 + ac0 * 8);
            pb  = *(const uint4*)(d.Bt + (size_t)(bn + br) * 256 + k0 + 32 + bc * 8);
        }
        __syncthreads();
        s16x8 af[2], bf[4];
#pragma unroll
        for (int mt = 0; mt < 2; ++mt)
            af[mt] = *(const s16x8*)(sA + (wave * 32 + mt * 16 + l16) * 40 + quad * 8);
#pragma unroll
        for (int nt = 0; nt < 4; ++nt)
            bf[nt] = *(const s16x8*)(sB + (nt * 16 + l16) * 40 + quad * 8);
#pragma unroll
        for (int mt = 0; mt < 2; ++mt)
#pragma unroll
            for (int nt = 0; nt < 4; ++nt)
                acc[mt][nt] = __builtin_amdgcn_mfma_f32_16x16x32_bf16(af[mt], bf[nt], acc[mt][nt], 0, 0, 0);
    }

#pragma unroll
    for (int mt = 0; mt < 2; ++mt) {
#pragma unroll
        for (int nt = 0; nt < 4; ++nt) {
            int n = bn + nt * 16 + l16;
            float bias_n = d.bias_on_m ? 0.f : d.bias[n];
#pragma unroll
            for (int r = 0; r < 4; ++r) {
                int m = bm + wave * 32 + mt * 16 + quad * 4 + r;
                float y = acc[mt][nt][r] + (d.bias_on_m ? d.bias[m] : bias_n);
                d.Yh[(size_t)m * d.N + n] = f2b(y * d.oscale);
            }
        }
    }
}

// ================= gated out-projection GEMM =========================================
template <bool STORE_BF16>
__global__ __launch_bounds__(256, 2) void gemm_out(
    const unsigned short* __restrict__ A, const unsigned short* __restrict__ Bt,
    const float* __restrict__ bias, float* __restrict__ Yf, unsigned short* __restrict__ Yh,
    int M, const float* __restrict__ gate, const float* __restrict__ resid, int rows_per_b) {
    __shared__ unsigned short sA[128 * 40];
    __shared__ unsigned short sB[64 * 40];
    const int tid = threadIdx.x;
    const int wave = tid >> 6, lane = tid & 63;
    const int quad = lane >> 4, l16 = lane & 15;
    const int bm = blockIdx.y * 128, bn = blockIdx.x * 64;
    const int ar0 = tid >> 2, ac0 = tid & 3;
    const int ar1 = (tid + 256) >> 2;
    const int br = tid >> 2, bc = tid & 3;

    f32x4 acc[2][4];
#pragma unroll
    for (int i = 0; i < 2; ++i)
#pragma unroll
        for (int k = 0; k < 4; ++k) acc[i][k] = (f32x4){0.f, 0.f, 0.f, 0.f};

    uint4 pa0 = *(const uint4*)(A + (size_t)(bm + ar0) * 256 + ac0 * 8);
    uint4 pa1 = *(const uint4*)(A + (size_t)(bm + ar1) * 256 + ac0 * 8);
    uint4 pb  = *(const uint4*)(Bt + (size_t)(bn + br) * 256 + bc * 8);

    for (int k0 = 0; k0 < 256; k0 += 32) {
        __syncthreads();
        *(uint4*)(sA + ar0 * 40 + ac0 * 8) = pa0;
        *(uint4*)(sA + ar1 * 40 + ac0 * 8) = pa1;
        *(uint4*)(sB + br * 40 + bc * 8) = pb;
        if (k0 < 224) {
            pa0 = *(const uint4*)(A + (size_t)(bm + ar0) * 256 + k0 + 32 + ac0 * 8);
            pa1 = *(const uint4*)(A + (size_t)(bm + ar1) * 256 + k0 + 32 + ac0 * 8);
            pb  = *(const uint4*)(Bt + (size_t)(bn + br) * 256 + k0 + 32 + bc * 8);
        }
        __syncthreads();
        s16x8 af[2], bf[4];
#pragma unroll
        for (int mt = 0; mt < 2; ++mt)
            af[mt] = *(const s16x8*)(sA + (wave * 32 + mt * 16 + l16) * 40 + quad * 8);
#pragma unroll
        for (int nt = 0; nt < 4; ++nt)
            bf[nt] = *(const s16x8*)(sB + (nt * 16 + l16) * 40 + quad * 8);
#pragma unroll
        for (int mt = 0; mt < 2; ++mt)
#pragma unroll
            for (int nt = 0; nt < 4; ++nt)
                acc[mt][nt] = __builtin_amdgcn_mfma_f32_16x16x32_bf16(af[mt], bf[nt], acc[mt][nt], 0, 0, 0);
    }

    const int b = bm / rows_per_b;
#pragma unroll
    for (int mt = 0; mt < 2; ++mt) {
#pragma unroll
        for (int nt = 0; nt < 4; ++nt) {
            int n = bn + nt * 16 + l16;
            float bias_n = bias[n];
            float g = gate[b * C + n];
#pragma unroll
            for (int r = 0; r < 4; ++r) {
                int m = bm + wave * 32 + mt * 16 + quad * 4 + r;
                float y = acc[mt][nt][r] + bias_n;
                float rv = resid[(size_t)m * C + n];
                y = g * y + (1.f - g) * rv;
                Yf[(size_t)m * C + n] = y;
                if (STORE_BF16) Yh[(size_t)m * C + n] = f2b(y);
            }
        }
    }
}

// ================= MFMA flash attention v3 ============================================
// LDS-staged K/V (register-prefetched across the barrier), 16 q/wave, 64 q/block.
// Odd-dword LDS strides (34/66/70 shorts) to spread banks; one batched P round-trip
// per 64-key chunk. Q pre-scaled by scale*log2e; exp2 softmax, no max subtraction.
__global__ __launch_bounds__(256, 8) void attn_mfma(
    const unsigned short* __restrict__ Q, const unsigned short* __restrict__ K,
    const unsigned short* __restrict__ Vt, unsigned short* __restrict__ O,
    int Nq, int Nk, int vtStride) {
    __shared__ unsigned short sK[64 * 34];      // 64 keys x 32d (+2 pad)
    __shared__ unsigned short sVt[32 * 66];     // 32 d x 64 keys (+2 pad)
    __shared__ unsigned short sP[4][16 * 70];   // per-wave: 16 q x 64 keys (+6 pad)
    const int tid = threadIdx.x;
    const int wave = tid >> 6, lane = tid & 63;
    const int quad = lane >> 4, l16 = lane & 15;
    const int b = blockIdx.z, h = blockIdx.y;
    const int q0 = blockIdx.x * 64 + wave * 16;

    s16x8 qf = *(const s16x8*)(Q + ((size_t)b * Nq + q0 + l16) * 256 + h * 32 + quad * 8);
    f32x4 oacc[2];
    oacc[0] = (f32x4){0.f, 0.f, 0.f, 0.f};
    oacc[1] = (f32x4){0.f, 0.f, 0.f, 0.f};
    float rs = 0.f;

    const int kr = tid >> 2, kc = tid & 3;      // K stage: 64 rows x 4 col-groups
    const int vr = tid >> 3, vc = tid & 7;      // V stage: 32 rows x 8 col-groups
    const unsigned short* Kb = K + (size_t)b * Nk * 256 + h * 32;
    const unsigned short* Vb = Vt + (size_t)(h * 32 + vr) * vtStride + (size_t)b * Nk;

    uint4 kreg = *(const uint4*)(Kb + (size_t)kr * 256 + kc * 8);
    uint4 vreg = *(const uint4*)(Vb + vc * 8);

    for (int k0 = 0; k0 < Nk; k0 += 64) {
        __syncthreads();
        *(uint4*)(sK + kr * 34 + kc * 8) = kreg;
        *(uint4*)(sVt + vr * 66 + vc * 8) = vreg;
        if (k0 + 64 < Nk) {
            kreg = *(const uint4*)(Kb + (size_t)(k0 + 64 + kr) * 256 + kc * 8);
            vreg = *(const uint4*)(Vb + k0 + 64 + vc * 8);
        }
        __syncthreads();

        unsigned short* p = &sP[wave][0];
        // all 4 QK tiles -> exp -> pack -> LDS write (batched; one wait before reads)
#pragma unroll
        for (int t = 0; t < 4; ++t) {
            s16x8 kf = *(const s16x8*)(sK + (t * 16 + l16) * 34 + quad * 8);
            f32x4 z = (f32x4){0.f, 0.f, 0.f, 0.f};
            f32x4 st = __builtin_amdgcn_mfma_f32_16x16x32_bf16(kf, qf, z, 0, 0, 0);
            float p0 = EXP2F(st[0]), p1 = EXP2F(st[1]);
            float p2 = EXP2F(st[2]), p3 = EXP2F(st[3]);
            rs += (p0 + p1) + (p2 + p3);
            uint2 pk;
            pk.x = pack2(p0, p1);
            pk.y = pack2(p2, p3);
            *(uint2*)(p + l16 * 70 + t * 16 + quad * 4) = pk;
        }
#pragma unroll
        for (int kg = 0; kg < 2; ++kg) {
            s16x8 pf = *(const s16x8*)(p + l16 * 70 + kg * 32 + quad * 8);
#pragma unroll
            for (int dh = 0; dh < 2; ++dh) {
                s16x8 vf = *(const s16x8*)(sVt + (dh * 16 + l16) * 66 + kg * 32 + quad * 8);
                oacc[dh] = __builtin_amdgcn_mfma_f32_16x16x32_bf16(pf, vf, oacc[dh], 0, 0, 0);
            }
        }
    }

    rs += __shfl_xor(rs, 16, 64);
    rs += __shfl_xor(rs, 32, 64);
    float inv = 1.f / rs;
#pragma unroll
    for (int rr = 0; rr < 4; ++rr) {
        float iq = __shfl(inv, quad * 4 + rr, 64);
#pragma unroll
        for (int dh = 0; dh < 2; ++dh)
            O[((size_t)b * Nq + q0 + quad * 4 + rr) * 256 + h * 32 + dh * 16 + l16] =
                f2b(oacc[dh][rr] * iq);
    }
}

extern "C" void kernel_launch(void* const* d_in, const int* in_sizes, int n_in,
                              void* d_out, int out_size, void* d_ws, size_t ws_size,
                              hipStream_t stream) {
    (void)in_sizes; (void)n_in; (void)out_size; (void)ws_size;
    const float* img  = (const float*)d_in[0];
    const float* aud  = (const float*)d_in[1];
    const float* Wq_i = (const float*)d_in[2];  const float* bq_i = (const float*)d_in[3];
    const float* Wk_i = (const float*)d_in[4];  const float* bk_i = (const float*)d_in[5];
    const float* Wv_i = (const float*)d_in[6];  const float* bv_i = (const float*)d_in[7];
    const float* Wo_i = (const float*)d_in[8];  const float* bo_i = (const float*)d_in[9];
    const float* Wq_a = (const float*)d_in[10]; const float* bq_a = (const float*)d_in[11];
    const float* Wk_a = (const float*)d_in[12]; const float* bk_a = (const float*)d_in[13];
    const float* Wv_a = (const float*)d_in[14]; const float* bv_a = (const float*)d_in[15];
    const float* Wo_a = (const float*)d_in[16]; const float* bo_a = (const float*)d_in[17];
    // d_in[18..25]: cond-MLP — dead code (uniform softmax bias cancels)
    const float* Wg_i = (const float*)d_in[26]; const float* bg_i = (const float*)d_in[27];
    const float* Wg_a = (const float*)d_in[28]; const float* bg_a = (const float*)d_in[29];

    const int B = 16, Nv = 1024, Na = 512;
    const int Mi = B * Nv, Ma = B * Na;
    const size_t MiC = (size_t)Mi * C;
    const size_t MaC = (size_t)Ma * C;

    float* out_img = (float*)d_out;
    float* out_aud = out_img + MiC;

    unsigned short* wsu = (unsigned short*)d_ws;
    unsigned short* R1 = wsu;              // imgb [Mi][256]
    unsigned short* R2 = R1 + MiC;         // Ki -> Fi
    unsigned short* R3 = R2 + MiC;         // Vt_i [256][Mi]
    unsigned short* R8 = R3 + MiC;         // Qi
    unsigned short* R4 = R8 + MiC;         // audb
    unsigned short* R5 = R4 + MaC;         // Qa -> Ka
    unsigned short* R6 = R5 + MaC;         // Fa -> Vt_a [256][Ma]
    unsigned short* R7 = R6 + MaC;         // audio_out bf16
    unsigned short* wt = R7 + MaC;
    float* fws   = (float*)(wt + 8 * 65536);
    float* partI = fws;
    float* partA = partI + B * 8 * C;
    float* gI    = partA + B * 8 * C;
    float* gA    = gI + B * C;

    unsigned short* wtQa = wt + 0 * 65536;
    unsigned short* wtKi = wt + 1 * 65536;
    unsigned short* wtVi = wt + 2 * 65536;
    unsigned short* wtOa = wt + 3 * 65536;
    unsigned short* wtKa = wt + 4 * 65536;
    unsigned short* wtVa = wt + 5 * 65536;
    unsigned short* wtQi = wt + 6 * 65536;
    unsigned short* wtOi = wt + 7 * 65536;

    const float qs = 0.17677669529663687f * 1.4426950408889634f;  // (1/sqrt(32))*log2e
    dim3 blk(256);

    // ---- 1: prep (cast+mean img/aud + 8 weight transposes) ----
    WPtrs wp;
    wp.src[0] = Wq_a; wp.dst[0] = wtQa;
    wp.src[1] = Wk_i; wp.dst[1] = wtKi;
    wp.src[2] = Wv_i; wp.dst[2] = wtVi;
    wp.src[3] = Wo_a; wp.dst[3] = wtOa;
    wp.src[4] = Wk_a; wp.dst[4] = wtKa;
    wp.src[5] = Wv_a; wp.dst[5] = wtVa;
    wp.src[6] = Wq_i; wp.dst[6] = wtQi;
    wp.src[7] = Wo_i; wp.dst[7] = wtOi;
    prep_kernel<<<288, blk, 0, stream>>>(img, aud, R1, R4, partI, partA, wp);

    // ---- 2: Qa + Ki + Vt_i + Qi projections + both gates, one launch ----
    GArgs g1 = {};
    g1.d[0] = {R4,   wtQa, bq_a, R5, 256,   0,    2, 0, qs };  // Qa: 64x4 = 256 blocks
    g1.d[1] = {R1,   wtKi, bk_i, R2, 256,   256,  2, 0, 1.f};  // Ki: 128x4 = 512
    g1.d[2] = {wtVi, R1,   bv_i, R3, 16384, 768,  8, 1, 1.f};  // Vt_i: 2x256 = 512
    g1.d[3] = {R1,   wtQi, bq_i, R8, 256,   1280, 2, 0, qs };  // Qi: 128x4 = 512
    g1.off1 = 256; g1.off2 = 768; g1.off3 = 1280; g1.gemm_total = 1792;
    g1.partI = partI; g1.partA = partA;
    g1.WgI = Wg_i; g1.WgA = Wg_a; g1.bgI = bg_i; g1.bgA = bg_a;
    g1.gI = gI; g1.gA = gA; g1.invNv = 1.f / Nv; g1.invNa = 1.f / Na;
    gemm_multi<<<1792 + 32, blk, 0, stream>>>(g1);

    // ---- 3: audio attention ----
    attn_mfma<<<dim3(Na / 64, 8, B), blk, 0, stream>>>(R5, R2, R3, R6, Na, Nv, Mi);

    // ---- 4: audio out-proj + gate + residual (fp32 out + bf16 feed) ----
    gemm_out<true><<<dim3(4, Ma / 128), blk, 0, stream>>>(R6, wtOa, bo_a, out_aud, R7, Ma, gA, aud, Na);

    // ---- 5: Ka + Vt_a from updated audio ----
    GArgs g2 = {};
    g2.d[0] = {R7,   wtKa, bk_a, R5, 256,  0,   2, 0, 1.f};  // Ka: 64x4 = 256 blocks
    g2.d[1] = {wtVa, R7,   bv_a, R6, 8192, 256, 7, 1, 1.f};  // Vt_a: 2x128 = 256
    g2.off1 = 256; g2.off2 = 512; g2.off3 = 512; g2.gemm_total = 512;
    gemm_multi<<<512, blk, 0, stream>>>(g2);

    // ---- 6: image attention ----
    attn_mfma<<<dim3(Nv / 64, 8, B), blk, 0, stream>>>(R8, R5, R6, R2, Nv, Na, Ma);

    // ---- 7: image out-proj + gate + residual ----
    gemm_out<false><<<dim3(4, Mi / 128), blk, 0, stream>>>(R2, wtOi, bo_i, out_img, nullptr, Mi, gI, img, Nv);
}

// Round 6
// 241.664 us; speedup vs baseline: 1.3292x; 1.3292x over previous
//
#include <hip/hip_runtime.h>

#define C 256

typedef short s16x8 __attribute__((ext_vector_type(8)));
typedef float f32x4 __attribute__((ext_vector_type(4)));

#if __has_builtin(__builtin_amdgcn_exp2f)
#define EXP2F __builtin_amdgcn_exp2f
#else
#define EXP2F exp2f
#endif

__device__ __forceinline__ unsigned short f2b(float f) {
    unsigned u = __float_as_uint(f);
    unsigned r = (u + 0x7fffu + ((u >> 16) & 1u)) >> 16;
    return (unsigned short)r;
}

// pack bf16(a) lo16, bf16(b) hi16 (round-half-up) — one v_perm_b32
__device__ __forceinline__ unsigned pack2(float a, float b) {
    return __builtin_amdgcn_perm(__float_as_uint(b) + 0x8000u,
                                 __float_as_uint(a) + 0x8000u, 0x07060302u);
}

// ================= prep: cast+mean (img, aud) + weight transpose, one launch ==========
struct WPtrs { const float* src[8]; unsigned short* dst[8]; };

__device__ __forceinline__ void cast_mean_body(
    const float* __restrict__ x, unsigned short* __restrict__ y, float* __restrict__ part,
    int N, int nseg, int b, int seg, int tid) {
    __shared__ float red[4][C];
    int cg = tid & 63, rg = tid >> 6;
    int iters = nseg >> 2;
    const float* xp = x + ((size_t)b * N + (size_t)seg * nseg + rg) * C + cg * 4;
    unsigned short* yp = y + ((size_t)b * N + (size_t)seg * nseg + rg) * C + cg * 4;
    float s0 = 0.f, s1 = 0.f, s2 = 0.f, s3 = 0.f;
    for (int i = 0; i < iters; ++i) {
        float4 v = *(const float4*)(xp + (size_t)i * 4 * C);
        s0 += v.x; s1 += v.y; s2 += v.z; s3 += v.w;
        ushort4 o; o.x = f2b(v.x); o.y = f2b(v.y); o.z = f2b(v.z); o.w = f2b(v.w);
        *(ushort4*)(yp + (size_t)i * 4 * C) = o;
    }
    float4 s4 = {s0, s1, s2, s3};
    *(float4*)&red[rg][cg * 4] = s4;
    __syncthreads();
    float s = red[0][tid] + red[1][tid] + red[2][tid] + red[3][tid];
    part[(b * 8 + seg) * C + tid] = s;
}

__global__ void prep_kernel(const float* __restrict__ img, const float* __restrict__ aud,
                            unsigned short* __restrict__ R1, unsigned short* __restrict__ R4,
                            float* __restrict__ partI, float* __restrict__ partA, WPtrs wp) {
    int x = blockIdx.x, tid = threadIdx.x;
    if (x < 128) {
        cast_mean_body(img, R1, partI, 1024, 128, x >> 3, x & 7, tid);
    } else if (x < 256) {
        int id = x - 128;
        cast_mean_body(aud, R4, partA, 512, 64, id >> 3, id & 7, tid);
    } else {
        int id = x - 256;                 // 0..31
        const float* W = wp.src[id >> 2];
        unsigned short* Wt = wp.dst[id >> 2];
        int n = (id & 3) * 64 + (tid & 63);
        int k0 = (tid >> 6) * 64;
#pragma unroll
        for (int kk = 0; kk < 64; kk += 4) {
            float a0 = W[(size_t)(k0 + kk + 0) * C + n];
            float a1 = W[(size_t)(k0 + kk + 1) * C + n];
            float a2 = W[(size_t)(k0 + kk + 2) * C + n];
            float a3 = W[(size_t)(k0 + kk + 3) * C + n];
            ushort4 o; o.x = f2b(a0); o.y = f2b(a1); o.z = f2b(a2); o.w = f2b(a3);
            *(ushort4*)(Wt + (size_t)n * C + k0 + kk) = o;
        }
    }
}

// ================= multi-GEMM: several NT bf16 GEMMs (+ gates) in one launch ==========
struct GDesc {
    const unsigned short* A;   // [M][256]
    const unsigned short* Bt;  // [N][256]
    const float* bias;
    unsigned short* Yh;        // [M][N]
    int N;
    int start;                 // first block id
    int lnb;                   // log2(blocks along n)
    int bias_on_m;
    float oscale;
};
struct GArgs {
    GDesc d[4];
    int off1, off2, off3;      // desc start boundaries
    int gemm_total;            // blocks >= this do gate work
    const float* partI; const float* partA;
    const float* WgI; const float* WgA;
    const float* bgI; const float* bgA;
    float* gI; float* gA;
    float invNv, invNa;
};

__global__ __launch_bounds__(256, 2) void gemm_multi(GArgs ga) {
    __shared__ unsigned short sA[128 * 40];
    __shared__ unsigned short sB[64 * 40];
    const int bid = blockIdx.x;
    const int tid = threadIdx.x;

    if (bid >= ga.gemm_total) {  // ---- gate blocks: sigmoid(mean @ Wg + bg) ----
        float* t = (float*)sA;
        int id = bid - ga.gemm_total;
        int b = id >> 1, which = id & 1;
        const float* part = which ? ga.partA : ga.partI;
        const float* Wg = which ? ga.WgA : ga.WgI;
        const float* bg = which ? ga.bgA : ga.bgI;
        float* g = which ? ga.gA : ga.gI;
        float invN = which ? ga.invNa : ga.invNv;
        float s = 0.f;
#pragma unroll
        for (int j = 0; j < 8; ++j) s += part[(b * 8 + j) * C + tid];
        t[tid] = s * invN;
        __syncthreads();
        float acc = bg[tid];
#pragma unroll 8
        for (int k = 0; k < C; ++k) acc += t[k] * Wg[k * C + tid];
        g[b * C + tid] = 1.f / (1.f + __expf(-acc));
        return;
    }

    const int j = (bid >= ga.off1) + (bid >= ga.off2) + (bid >= ga.off3);
    const GDesc d = ga.d[j];
    const int local = bid - d.start;
    const int bn = (local & ((1 << d.lnb) - 1)) * 64;
    const int bm = (local >> d.lnb) * 128;

    const int wave = tid >> 6, lane = tid & 63;
    const int quad = lane >> 4, l16 = lane & 15;
    const int ar0 = tid >> 2, ac0 = tid & 3;
    const int ar1 = (tid + 256) >> 2;
    const int br = tid >> 2, bc = tid & 3;

    f32x4 acc[2][4];
#pragma unroll
    for (int i = 0; i < 2; ++i)
#pragma unroll
        for (int k = 0; k < 4; ++k) acc[i][k] = (f32x4){0.f, 0.f, 0.f, 0.f};

    uint4 pa0 = *(const uint4*)(d.A + (size_t)(bm + ar0) * 256 + ac0 * 8);
    uint4 pa1 = *(const uint4*)(d.A + (size_t)(bm + ar1) * 256 + ac0 * 8);
    uint4 pb  = *(const uint4*)(d.Bt + (size_t)(bn + br) * 256 + bc * 8);

    for (int k0 = 0; k0 < 256; k0 += 32) {
        __syncthreads();
        *(uint4*)(sA + ar0 * 40 + ac0 * 8) = pa0;
        *(uint4*)(sA + ar1 * 40 + ac0 * 8) = pa1;
        *(uint4*)(sB + br * 40 + bc * 8) = pb;
        if (k0 < 224) {
            pa0 = *(const uint4*)(d.A + (size_t)(bm + ar0) * 256 + k0 + 32 + ac0 * 8);
            pa1 = *(const uint4*)(d.A + (size_t)(bm + ar1) * 256 + k0 + 32 + ac0 * 8);
            pb  = *(const uint4*)(d.Bt + (size_t)(bn + br) * 256 + k0 + 32 + bc * 8);
        }
        __syncthreads();
        s16x8 af[2], bf[4];
#pragma unroll
        for (int mt = 0; mt < 2; ++mt)
            af[mt] = *(const s16x8*)(sA + (wave * 32 + mt * 16 + l16) * 40 + quad * 8);
#pragma unroll
        for (int nt = 0; nt < 4; ++nt)
            bf[nt] = *(const s16x8*)(sB + (nt * 16 + l16) * 40 + quad * 8);
#pragma unroll
        for (int mt = 0; mt < 2; ++mt)
#pragma unroll
            for (int nt = 0; nt < 4; ++nt)
                acc[mt][nt] = __builtin_amdgcn_mfma_f32_16x16x32_bf16(af[mt], bf[nt], acc[mt][nt], 0, 0, 0);
    }

#pragma unroll
    for (int mt = 0; mt < 2; ++mt) {
#pragma unroll
        for (int nt = 0; nt < 4; ++nt) {
            int n = bn + nt * 16 + l16;
            float bias_n = d.bias_on_m ? 0.f : d.bias[n];
#pragma unroll
            for (int r = 0; r < 4; ++r) {
                int m = bm + wave * 32 + mt * 16 + quad * 4 + r;
                float y = acc[mt][nt][r] + (d.bias_on_m ? d.bias[m] : bias_n);
                d.Yh[(size_t)m * d.N + n] = f2b(y * d.oscale);
            }
        }
    }
}

// ================= gated out-projection GEMM =========================================
template <bool STORE_BF16>
__global__ __launch_bounds__(256, 2) void gemm_out(
    const unsigned short* __restrict__ A, const unsigned short* __restrict__ Bt,
    const float* __restrict__ bias, float* __restrict__ Yf, unsigned short* __restrict__ Yh,
    int M, const float* __restrict__ gate, const float* __restrict__ resid, int rows_per_b) {
    __shared__ unsigned short sA[128 * 40];
    __shared__ unsigned short sB[64 * 40];
    const int tid = threadIdx.x;
    const int wave = tid >> 6, lane = tid & 63;
    const int quad = lane >> 4, l16 = lane & 15;
    const int bm = blockIdx.y * 128, bn = blockIdx.x * 64;
    const int ar0 = tid >> 2, ac0 = tid & 3;
    const int ar1 = (tid + 256) >> 2;
    const int br = tid >> 2, bc = tid & 3;

    f32x4 acc[2][4];
#pragma unroll
    for (int i = 0; i < 2; ++i)
#pragma unroll
        for (int k = 0; k < 4; ++k) acc[i][k] = (f32x4){0.f, 0.f, 0.f, 0.f};

    uint4 pa0 = *(const uint4*)(A + (size_t)(bm + ar0) * 256 + ac0 * 8);
    uint4 pa1 = *(const uint4*)(A + (size_t)(bm + ar1) * 256 + ac0 * 8);
    uint4 pb  = *(const uint4*)(Bt + (size_t)(bn + br) * 256 + bc * 8);

    for (int k0 = 0; k0 < 256; k0 += 32) {
        __syncthreads();
        *(uint4*)(sA + ar0 * 40 + ac0 * 8) = pa0;
        *(uint4*)(sA + ar1 * 40 + ac0 * 8) = pa1;
        *(uint4*)(sB + br * 40 + bc * 8) = pb;
        if (k0 < 224) {
            pa0 = *(const uint4*)(A + (size_t)(bm + ar0) * 256 + k0 + 32 + ac0 * 8);
            pa1 = *(const uint4*)(A + (size_t)(bm + ar1) * 256 + k0 + 32 + ac0 * 8);
            pb  = *(const uint4*)(Bt + (size_t)(bn + br) * 256 + k0 + 32 + bc * 8);
        }
        __syncthreads();
        s16x8 af[2], bf[4];
#pragma unroll
        for (int mt = 0; mt < 2; ++mt)
            af[mt] = *(const s16x8*)(sA + (wave * 32 + mt * 16 + l16) * 40 + quad * 8);
#pragma unroll
        for (int nt = 0; nt < 4; ++nt)
            bf[nt] = *(const s16x8*)(sB + (nt * 16 + l16) * 40 + quad * 8);
#pragma unroll
        for (int mt = 0; mt < 2; ++mt)
#pragma unroll
            for (int nt = 0; nt < 4; ++nt)
                acc[mt][nt] = __builtin_amdgcn_mfma_f32_16x16x32_bf16(af[mt], bf[nt], acc[mt][nt], 0, 0, 0);
    }

    const int b = bm / rows_per_b;
#pragma unroll
    for (int mt = 0; mt < 2; ++mt) {
#pragma unroll
        for (int nt = 0; nt < 4; ++nt) {
            int n = bn + nt * 16 + l16;
            float bias_n = bias[n];
            float g = gate[b * C + n];
#pragma unroll
            for (int r = 0; r < 4; ++r) {
                int m = bm + wave * 32 + mt * 16 + quad * 4 + r;
                float y = acc[mt][nt][r] + bias_n;
                float rv = resid[(size_t)m * C + n];
                y = g * y + (1.f - g) * rv;
                Yf[(size_t)m * C + n] = y;
                if (STORE_BF16) Yh[(size_t)m * C + n] = f2b(y);
            }
        }
    }
}

// ================= MFMA flash attention (r3 structure + depth-2 prefetch + XCD swizzle)
// Strides 40/72/40 shorts = 20/36/20 dwords: verified uniform bank loads (mod 32).
// 1D swizzled grid: bh = (id&7) + 8*(slot>>lnxb) keeps all q-blocks of one (b,h)
// on one XCD so its K/V slice stays in that XCD's L2.
__global__ __launch_bounds__(256) void attn_mfma(
    const unsigned short* __restrict__ Q, const unsigned short* __restrict__ K,
    const unsigned short* __restrict__ Vt, unsigned short* __restrict__ O,
    int Nq, int Nk, int vtStride, int lnxb) {
    __shared__ unsigned short sK[64 * 40];
    __shared__ unsigned short sVt[32 * 72];
    __shared__ unsigned short sP[4][16 * 40];
    const int tid = threadIdx.x;
    const int wave = tid >> 6, lane = tid & 63;
    const int quad = lane >> 4, l16 = lane & 15;
    const int id = blockIdx.x;
    const int slot = id >> 3;
    const int bh = (id & 7) + 8 * (slot >> lnxb);
    const int xb = slot & ((1 << lnxb) - 1);
    const int b = bh >> 3, h = bh & 7;
    const int q0 = xb * 64 + wave * 16;

    s16x8 qf = *(const s16x8*)(Q + ((size_t)b * Nq + q0 + l16) * 256 + h * 32 + quad * 8);
    f32x4 oacc[2];
    oacc[0] = (f32x4){0.f, 0.f, 0.f, 0.f};
    oacc[1] = (f32x4){0.f, 0.f, 0.f, 0.f};
    float rs = 0.f;

    const int kr = tid >> 2, kc = tid & 3;      // K stage: 64 rows x 4 col-groups
    const int vr = tid >> 3, vc = tid & 7;      // V stage: 32 rows x 8 col-groups
    const unsigned short* Kb = K + (size_t)b * Nk * 256 + h * 32;
    const unsigned short* Vb = Vt + (size_t)(h * 32 + vr) * vtStride + (size_t)b * Nk;

    // depth-2 register prefetch of K/V chunks
    uint4 ka = *(const uint4*)(Kb + (size_t)kr * 256 + kc * 8);
    uint4 va = *(const uint4*)(Vb + vc * 8);
    const int n1 = (64 < Nk) ? 64 : 0;
    uint4 kb = *(const uint4*)(Kb + (size_t)(n1 + kr) * 256 + kc * 8);
    uint4 vb = *(const uint4*)(Vb + n1 + vc * 8);

    for (int k0 = 0; k0 < Nk; k0 += 64) {
        __syncthreads();
        *(uint4*)(sK + kr * 40 + kc * 8) = ka;
        *(uint4*)(sVt + vr * 72 + vc * 8) = va;
        ka = kb; va = vb;
        int np = k0 + 128; if (np >= Nk) np = Nk - 64;
        kb = *(const uint4*)(Kb + (size_t)(np + kr) * 256 + kc * 8);
        vb = *(const uint4*)(Vb + np + vc * 8);
        __syncthreads();

        unsigned short* p = &sP[wave][0];
#pragma unroll
        for (int kg = 0; kg < 2; ++kg) {
#pragma unroll
            for (int kt = 0; kt < 2; ++kt) {
                s16x8 kf = *(const s16x8*)(sK + (kg * 32 + kt * 16 + l16) * 40 + quad * 8);
                f32x4 z = (f32x4){0.f, 0.f, 0.f, 0.f};
                f32x4 st = __builtin_amdgcn_mfma_f32_16x16x32_bf16(kf, qf, z, 0, 0, 0);
                float p0 = EXP2F(st[0]), p1 = EXP2F(st[1]);
                float p2 = EXP2F(st[2]), p3 = EXP2F(st[3]);
                rs += (p0 + p1) + (p2 + p3);
                uint2 pk;
                pk.x = pack2(p0, p1);
                pk.y = pack2(p2, p3);
                *(uint2*)(p + l16 * 40 + kt * 16 + quad * 4) = pk;
            }
            s16x8 pf = *(const s16x8*)(p + l16 * 40 + quad * 8);
#pragma unroll
            for (int dh = 0; dh < 2; ++dh) {
                s16x8 vf = *(const s16x8*)(sVt + (dh * 16 + l16) * 72 + kg * 32 + quad * 8);
                oacc[dh] = __builtin_amdgcn_mfma_f32_16x16x32_bf16(pf, vf, oacc[dh], 0, 0, 0);
            }
        }
    }

    rs += __shfl_xor(rs, 16, 64);
    rs += __shfl_xor(rs, 32, 64);
    float inv = 1.f / rs;
#pragma unroll
    for (int rr = 0; rr < 4; ++rr) {
        float iq = __shfl(inv, quad * 4 + rr, 64);
#pragma unroll
        for (int dh = 0; dh < 2; ++dh)
            O[((size_t)b * Nq + q0 + quad * 4 + rr) * 256 + h * 32 + dh * 16 + l16] =
                f2b(oacc[dh][rr] * iq);
    }
}

extern "C" void kernel_launch(void* const* d_in, const int* in_sizes, int n_in,
                              void* d_out, int out_size, void* d_ws, size_t ws_size,
                              hipStream_t stream) {
    (void)in_sizes; (void)n_in; (void)out_size; (void)ws_size;
    const float* img  = (const float*)d_in[0];
    const float* aud  = (const float*)d_in[1];
    const float* Wq_i = (const float*)d_in[2];  const float* bq_i = (const float*)d_in[3];
    const float* Wk_i = (const float*)d_in[4];  const float* bk_i = (const float*)d_in[5];
    const float* Wv_i = (const float*)d_in[6];  const float* bv_i = (const float*)d_in[7];
    const float* Wo_i = (const float*)d_in[8];  const float* bo_i = (const float*)d_in[9];
    const float* Wq_a = (const float*)d_in[10]; const float* bq_a = (const float*)d_in[11];
    const float* Wk_a = (const float*)d_in[12]; const float* bk_a = (const float*)d_in[13];
    const float* Wv_a = (const float*)d_in[14]; const float* bv_a = (const float*)d_in[15];
    const float* Wo_a = (const float*)d_in[16]; const float* bo_a = (const float*)d_in[17];
    // d_in[18..25]: cond-MLP — dead code (uniform softmax bias cancels)
    const float* Wg_i = (const float*)d_in[26]; const float* bg_i = (const float*)d_in[27];
    const float* Wg_a = (const float*)d_in[28]; const float* bg_a = (const float*)d_in[29];

    const int B = 16, Nv = 1024, Na = 512;
    const int Mi = B * Nv, Ma = B * Na;
    const size_t MiC = (size_t)Mi * C;
    const size_t MaC = (size_t)Ma * C;

    float* out_img = (float*)d_out;
    float* out_aud = out_img + MiC;

    unsigned short* wsu = (unsigned short*)d_ws;
    unsigned short* R1 = wsu;              // imgb [Mi][256]
    unsigned short* R2 = R1 + MiC;         // Ki -> Fi
    unsigned short* R3 = R2 + MiC;         // Vt_i [256][Mi]
    unsigned short* R8 = R3 + MiC;         // Qi
    unsigned short* R4 = R8 + MiC;         // audb
    unsigned short* R5 = R4 + MaC;         // Qa -> Ka
    unsigned short* R6 = R5 + MaC;         // Fa -> Vt_a [256][Ma]
    unsigned short* R7 = R6 + MaC;         // audio_out bf16
    unsigned short* wt = R7 + MaC;
    float* fws   = (float*)(wt + 8 * 65536);
    float* partI = fws;
    float* partA = partI + B * 8 * C;
    float* gI    = partA + B * 8 * C;
    float* gA    = gI + B * C;

    unsigned short* wtQa = wt + 0 * 65536;
    unsigned short* wtKi = wt + 1 * 65536;
    unsigned short* wtVi = wt + 2 * 65536;
    unsigned short* wtOa = wt + 3 * 65536;
    unsigned short* wtKa = wt + 4 * 65536;
    unsigned short* wtVa = wt + 5 * 65536;
    unsigned short* wtQi = wt + 6 * 65536;
    unsigned short* wtOi = wt + 7 * 65536;

    const float qs = 0.17677669529663687f * 1.4426950408889634f;  // (1/sqrt(32))*log2e
    dim3 blk(256);

    // ---- 1: prep (cast+mean img/aud + 8 weight transposes) ----
    WPtrs wp;
    wp.src[0] = Wq_a; wp.dst[0] = wtQa;
    wp.src[1] = Wk_i; wp.dst[1] = wtKi;
    wp.src[2] = Wv_i; wp.dst[2] = wtVi;
    wp.src[3] = Wo_a; wp.dst[3] = wtOa;
    wp.src[4] = Wk_a; wp.dst[4] = wtKa;
    wp.src[5] = Wv_a; wp.dst[5] = wtVa;
    wp.src[6] = Wq_i; wp.dst[6] = wtQi;
    wp.src[7] = Wo_i; wp.dst[7] = wtOi;
    prep_kernel<<<288, blk, 0, stream>>>(img, aud, R1, R4, partI, partA, wp);

    // ---- 2: Qa + Ki + Vt_i + Qi projections + both gates, one launch ----
    GArgs g1 = {};
    g1.d[0] = {R4,   wtQa, bq_a, R5, 256,   0,    2, 0, qs };  // Qa: 64x4 = 256 blocks
    g1.d[1] = {R1,   wtKi, bk_i, R2, 256,   256,  2, 0, 1.f};  // Ki: 128x4 = 512
    g1.d[2] = {wtVi, R1,   bv_i, R3, 16384, 768,  8, 1, 1.f};  // Vt_i: 2x256 = 512
    g1.d[3] = {R1,   wtQi, bq_i, R8, 256,   1280, 2, 0, qs };  // Qi: 128x4 = 512
    g1.off1 = 256; g1.off2 = 768; g1.off3 = 1280; g1.gemm_total = 1792;
    g1.partI = partI; g1.partA = partA;
    g1.WgI = Wg_i; g1.WgA = Wg_a; g1.bgI = bg_i; g1.bgA = bg_a;
    g1.gI = gI; g1.gA = gA; g1.invNv = 1.f / Nv; g1.invNa = 1.f / Na;
    gemm_multi<<<1792 + 32, blk, 0, stream>>>(g1);

    // ---- 3: audio attention (128 bh * 8 q-blocks, XCD-swizzled) ----
    attn_mfma<<<128 * (Na / 64), blk, 0, stream>>>(R5, R2, R3, R6, Na, Nv, Mi, 3);

    // ---- 4: audio out-proj + gate + residual (fp32 out + bf16 feed) ----
    gemm_out<true><<<dim3(4, Ma / 128), blk, 0, stream>>>(R6, wtOa, bo_a, out_aud, R7, Ma, gA, aud, Na);

    // ---- 5: Ka + Vt_a from updated audio ----
    GArgs g2 = {};
    g2.d[0] = {R7,   wtKa, bk_a, R5, 256,  0,   2, 0, 1.f};  // Ka: 64x4 = 256 blocks
    g2.d[1] = {wtVa, R7,   bv_a, R6, 8192, 256, 7, 1, 1.f};  // Vt_a: 2x128 = 256
    g2.off1 = 256; g2.off2 = 512; g2.off3 = 512; g2.gemm_total = 512;
    gemm_multi<<<512, blk, 0, stream>>>(g2);

    // ---- 6: image attention (128 bh * 16 q-blocks, XCD-swizzled) ----
    attn_mfma<<<128 * (Nv / 64), blk, 0, stream>>>(R8, R5, R6, R2, Nv, Na, Ma, 4);

    // ---- 7: image out-proj + gate + residual ----
    gemm_out<false><<<dim3(4, Mi / 128), blk, 0, stream>>>(R2, wtOi, bo_i, out_img, nullptr, Mi, gI, img, Nv);
}